// Round 2
// 885.035 us; speedup vs baseline: 1.1783x; 1.1783x over previous
//
#include <hip/hip_runtime.h>
#include <stdint.h>

#define M_DIM 8192
#define N_DIM 11008
#define K_DIM 4096
#define KB_PACK 2048          // packed int32 (one byte each) per W row

// ---- 8-phase 256^2 template geometry (i8: BK=128 bytes == bf16 template's BK=64) ----
#define BM 256
#define BN 256
#define BK 128
#define NKT (K_DIM / BK)      // 32
#define THREADS 512

typedef __attribute__((ext_vector_type(4))) int   i32x4;
typedef __attribute__((ext_vector_type(4))) float f32x4;

// -------- async global->LDS (16B per lane; LDS dest = wave-uniform base + lane*16) --------
__device__ __forceinline__ void gload_lds16(const int8_t* g, int8_t* l) {
    __builtin_amdgcn_global_load_lds(
        (const __attribute__((address_space(1))) void*)g,
        (__attribute__((address_space(3))) void*)l,
        16, 0, 0);
}

// -------- pre-pass 1: per-row absmax int8 quantization of x --------
__global__ __launch_bounds__(256) void quant_x_kernel(const float* __restrict__ x,
                                                      int8_t* __restrict__ xq,
                                                      float* __restrict__ xs) {
    const int m   = blockIdx.x;
    const int tid = threadIdx.x;
    const float4* row = (const float4*)(x + (size_t)m * K_DIM);

    float4 v[4];
    float amax = 0.f;
#pragma unroll
    for (int i = 0; i < 4; ++i) {
        v[i] = row[i * 256 + tid];                       // coalesced
        amax = fmaxf(amax, fmaxf(fmaxf(fabsf(v[i].x), fabsf(v[i].y)),
                                 fmaxf(fabsf(v[i].z), fabsf(v[i].w))));
    }
#pragma unroll
    for (int off = 32; off > 0; off >>= 1)
        amax = fmaxf(amax, __shfl_xor(amax, off));
    __shared__ float red[4];
    if ((tid & 63) == 0) red[tid >> 6] = amax;
    __syncthreads();
    amax = fmaxf(fmaxf(red[0], red[1]), fmaxf(red[2], red[3]));

    const float safe = fmaxf(amax, 1e-20f);
    const float inv  = 127.f / safe;
    if (tid == 0) xs[m] = safe * (1.f / 127.f);

    int* out = (int*)(xq + (size_t)m * K_DIM);
#pragma unroll
    for (int i = 0; i < 4; ++i) {
        int c0 = __float2int_rn(v[i].x * inv);
        int c1 = __float2int_rn(v[i].y * inv);
        int c2 = __float2int_rn(v[i].z * inv);
        int c3 = __float2int_rn(v[i].w * inv);
        out[i * 256 + tid] = (c0 & 255) | ((c1 & 255) << 8) | ((c2 & 255) << 16) | (c3 << 24);
    }
}

// -------- pre-pass 2: unpack int4 (low nibble first) -> int8, scale folded into epilogue --------
__device__ __forceinline__ int unpack2(int v0, int v1) {
    int l0 = (((v0 & 15) ^ 8) - 8) & 255;
    int h0 = ((((v0 >> 4) & 15) ^ 8) - 8) & 255;
    int l1 = (((v1 & 15) ^ 8) - 8) & 255;
    int h1 = ((((v1 >> 4) & 15) ^ 8) - 8) & 255;
    return l0 | (h0 << 8) | (l1 << 16) | (h1 << 24);
}

__global__ __launch_bounds__(256) void unpack_w_kernel(const int* __restrict__ qw,
                                                       int8_t* __restrict__ wq) {
    size_t i = (size_t)blockIdx.x * 256 + threadIdx.x;
    const i32x4* q4 = (const i32x4*)qw;
    i32x4 a = q4[2 * i];
    i32x4 b = q4[2 * i + 1];
    i32x4 o;
    o.x = unpack2(a.x, a.y);
    o.y = unpack2(a.z, a.w);
    o.z = unpack2(b.x, b.y);
    o.w = unpack2(b.z, b.w);
    ((i32x4*)wq)[i] = o;
}

// ======================= main GEMM: 256x256 tile, 8-phase counted-vmcnt =======================
// LDS map (128 KiB): A buf0 @0, A buf1 @32K, B buf0 @64K, B buf1 @96K.
// Each buffer = [2 ksub][256 rows][64 B], ksub region = 16 KiB.
// Fragment read swizzle: col16' = col16 ^ ((row>>1)&3). Staging keeps LDS linear and
// inverse-swizzles the GLOBAL col (rule #21: same involution on source and read side).
// Race audit (R1): every STAGE targets a region whose last reads completed before the
// preceding barrier (reads are consumed by MFMA via lgkmcnt before the phase's closing
// barrier); every read is guarded by the vmcnt(6) one iter earlier (issue >=4 phases ahead).
// Tail re-stages byte-identical data so vmcnt counts stay exact.
__global__ __launch_bounds__(THREADS, 2) void gemm_i8_kernel(
    const int8_t* __restrict__ A,   // [M][K] i8
    const int8_t* __restrict__ B,   // [N][K] i8
    const float* __restrict__ xs,   // [M]
    const float* __restrict__ wsc,  // [N]
    const float* __restrict__ bias, // [N]
    float* __restrict__ C) {        // [M][N] fp32
    __shared__ int8_t lds[131072];

    const int tid  = threadIdx.x;
    const int lane = tid & 63;
    const int wid  = tid >> 6;
    const int wr   = wid >> 2;          // 0..1 : 128 output rows each
    const int wc   = wid & 3;           // 0..3 : 64 output cols each
    const int l15  = lane & 15;
    const int q    = lane >> 4;         // 16B k-chunk within ksub

    // XCD-aware swizzle: 1376 blocks = 8 XCDs * 172 (exact, bijective); M varies fastest
    const int lin = blockIdx.y * gridDim.x + blockIdx.x;
    const int swz = (lin & 7) * 172 + (lin >> 3);
    const int m0  = (swz & 31) * BM;    // 32 M-tiles
    const int n0  = (swz >> 5) * BN;    // 43 N-tiles

    // ---------- staging map: linear LDS dest (t*16), inverse-swizzled global source ----------
    const int sr   = tid >> 2;                                   // row 0..127 within half
    const int scol = (((tid & 3) ^ ((tid >> 3) & 3)) << 4);      // global col pre-swizzled
    const int8_t* gA = A + (size_t)(m0 + sr) * K_DIM + scol;
    const int8_t* gB = B + (size_t)(n0 + sr) * K_DIM + scol;
    const int sdst = tid * 16;

#define STAGE_A(KT, S) do { \
        const int8_t* g_ = gA + (size_t)(KT) * BK + (S) * 64; \
        int8_t* d_ = lds + (((KT) & 1) << 15) + ((S) << 14) + sdst; \
        gload_lds16(g_, d_); \
        gload_lds16(g_ + (size_t)128 * K_DIM, d_ + 8192); \
    } while (0)
#define STAGE_B(KT, S) do { \
        const int8_t* g_ = gB + (size_t)(KT) * BK + (S) * 64; \
        int8_t* d_ = lds + 65536 + (((KT) & 1) << 15) + ((S) << 14) + sdst; \
        gload_lds16(g_, d_); \
        gload_lds16(g_ + (size_t)128 * K_DIM, d_ + 8192); \
    } while (0)

    // ---------- fragment LDS offsets (swizzled read side) ----------
    // key match proof: stage key = (local_row>>1)&3; read row = {wr*128|wc*64} + {mi|ni}*16 + l15
    // (even + even + l15) -> (row>>1)&3 == (l15>>1)&3.
    const int fswz = ((q ^ ((l15 >> 1) & 3)) << 4);
    const int aoff = (wr * 128 + l15) * 64 + fswz;           // + bsel + ksub*16K + mi*1K
    const int boff = 65536 + (wc * 64 + l15) * 64 + fswz;    // + bsel + ksub*16K + ni*1K

#define LDA(MI, SS, BS) (*(const i32x4*)(lds + (aoff + (BS) + (SS) * 16384 + (MI) * 1024)))
#define LDB(NI, SS, BS) (*(const i32x4*)(lds + (boff + (BS) + (SS) * 16384 + (NI) * 1024)))
#define MFMA(D, AOP, BOP) D = __builtin_amdgcn_mfma_i32_16x16x64_i8(AOP, BOP, D, 0, 0, 0)

    i32x4 acc[8][4] = {};

    // ---------- prologue: tile0 complete + tile1 {A.k0, B.k0, A.k1} = 7 half-tiles ----------
    STAGE_A(0, 0); STAGE_B(0, 0); STAGE_A(0, 1); STAGE_B(0, 1);
    STAGE_A(1, 0); STAGE_B(1, 0); STAGE_A(1, 1);
    asm volatile("s_waitcnt vmcnt(6)" ::: "memory");   // tile0 (oldest 8) landed
    __builtin_amdgcn_s_barrier();

    // Steady-state: iter j stages p1 B(j+1,k1); p2 A(j+2,k0); p3 B(j+2,k0); p4 A(j+2,k1).
    // End-of-iter vmcnt(6) completes exactly tile j+1; 3 half-tiles (6 loads) stay in flight.
    for (int kt = 0; kt < NKT; ++kt) {
        const int bsel = (kt & 1) << 15;
        const int s1 = (kt + 1 < NKT) ? kt + 1 : kt - 1;   // same parity as kt+1
        const int s2 = (kt + 2 < NKT) ? kt + 2 : kt;       // same parity as kt+2
        i32x4 af[8], bf0, bf1, bf2, bf3;

        // ---- phase 1: ksub0 x ni{0,1} ----
#pragma unroll
        for (int mi = 0; mi < 8; ++mi) af[mi] = LDA(mi, 0, bsel);
        bf0 = LDB(0, 0, bsel);
        bf1 = LDB(1, 0, bsel);
        STAGE_B(s1, 1);
        __builtin_amdgcn_s_barrier();
        __builtin_amdgcn_s_setprio(1);
#pragma unroll
        for (int mi = 0; mi < 8; ++mi) { MFMA(acc[mi][0], af[mi], bf0); MFMA(acc[mi][1], af[mi], bf1); }
        __builtin_amdgcn_s_setprio(0);
        __builtin_amdgcn_s_barrier();

        // ---- phase 2: ksub0 x ni{2,3} ----
        bf2 = LDB(2, 0, bsel);
        bf3 = LDB(3, 0, bsel);
        STAGE_A(s2, 0);                      // A.k0 region freed after phase-1 barrier
        __builtin_amdgcn_s_barrier();
        __builtin_amdgcn_s_setprio(1);
#pragma unroll
        for (int mi = 0; mi < 8; ++mi) { MFMA(acc[mi][2], af[mi], bf2); MFMA(acc[mi][3], af[mi], bf3); }
        __builtin_amdgcn_s_setprio(0);
        __builtin_amdgcn_s_barrier();

        // ---- phase 3: ksub1 x ni{0,1} ----
#pragma unroll
        for (int mi = 0; mi < 8; ++mi) af[mi] = LDA(mi, 1, bsel);
        bf0 = LDB(0, 1, bsel);
        bf1 = LDB(1, 1, bsel);
        STAGE_B(s2, 0);                      // B.k0 freed after phase-2 barrier
        __builtin_amdgcn_s_barrier();
        __builtin_amdgcn_s_setprio(1);
#pragma unroll
        for (int mi = 0; mi < 8; ++mi) { MFMA(acc[mi][0], af[mi], bf0); MFMA(acc[mi][1], af[mi], bf1); }
        __builtin_amdgcn_s_setprio(0);
        __builtin_amdgcn_s_barrier();

        // ---- phase 4: ksub1 x ni{2,3} ----
        bf2 = LDB(2, 1, bsel);
        bf3 = LDB(3, 1, bsel);
        STAGE_A(s2, 1);                      // A.k1 freed after phase-3 barrier
        __builtin_amdgcn_s_barrier();
        __builtin_amdgcn_s_setprio(1);
#pragma unroll
        for (int mi = 0; mi < 8; ++mi) { MFMA(acc[mi][2], af[mi], bf2); MFMA(acc[mi][3], af[mi], bf3); }
        __builtin_amdgcn_s_setprio(0);
        asm volatile("s_waitcnt vmcnt(6)" ::: "memory");  // tile kt+1 fully landed
        __builtin_amdgcn_s_barrier();
    }

    // ---------- epilogue: C/D layout col = lane&15, row = (lane>>4)*4 + reg ----------
    const int row0 = q * 4;
    float sn[4], bv[4];
#pragma unroll
    for (int ni = 0; ni < 4; ++ni) {
        const int n = n0 + wc * 64 + ni * 16 + l15;
        sn[ni] = wsc[n];
        bv[ni] = bias[n];
    }
#pragma unroll
    for (int mi = 0; mi < 8; ++mi) {
        const int mbase = m0 + wr * 128 + mi * 16 + row0;
        float sm[4];
#pragma unroll
        for (int ri = 0; ri < 4; ++ri) sm[ri] = xs[mbase + ri];
#pragma unroll
        for (int ni = 0; ni < 4; ++ni) {
            const int n = n0 + wc * 64 + ni * 16 + l15;
            float* cp = C + (size_t)mbase * N_DIM + n;
#pragma unroll
            for (int ri = 0; ri < 4; ++ri)
                cp[(size_t)ri * N_DIM] = (float)acc[mi][ni][ri] * (sm[ri] * sn[ni]) + bv[ni];
        }
    }
#undef STAGE_A
#undef STAGE_B
#undef LDA
#undef LDB
#undef MFMA
}

// -------- fallback (only if workspace too small): naive fused dequant dot --------
__global__ void fallback_kernel(const float* __restrict__ x, const int* __restrict__ qw,
                                const float* __restrict__ sc, const float* __restrict__ bias,
                                float* __restrict__ y) {
    int m = blockIdx.y;
    int n = blockIdx.x * 256 + threadIdx.x;
    __shared__ float xsh[K_DIM];
    for (int k = threadIdx.x; k < K_DIM; k += 256) xsh[k] = x[(size_t)m * K_DIM + k];
    __syncthreads();
    if (n < N_DIM) {
        float acc = 0.f;
        const int* qr = qw + (size_t)n * KB_PACK;
        for (int kb = 0; kb < KB_PACK; ++kb) {
            int v = qr[kb] & 255;
            int lo = v & 15; lo -= (lo & 8) << 1;
            int hi = (v >> 4) & 15; hi -= (hi & 8) << 1;
            acc += xsh[2 * kb] * (float)lo + xsh[2 * kb + 1] * (float)hi;
        }
        y[(size_t)m * N_DIM + n] = acc * sc[n] + bias[n];
    }
}

extern "C" void kernel_launch(void* const* d_in, const int* in_sizes, int n_in,
                              void* d_out, int out_size, void* d_ws, size_t ws_size,
                              hipStream_t stream) {
    const float* x    = (const float*)d_in[0];
    const int*   qw   = (const int*)d_in[1];
    const float* sc   = (const float*)d_in[2];
    const float* bias = (const float*)d_in[3];
    float*       y    = (float*)d_out;

    const size_t xq_bytes = (size_t)M_DIM * K_DIM;            // 33.5 MB i8
    const size_t wq_bytes = (size_t)N_DIM * K_DIM;            // 45 MB i8
    const size_t xs_bytes = (size_t)M_DIM * sizeof(float);
    const size_t need = xq_bytes + wq_bytes + xs_bytes;

    if (ws_size >= need) {
        int8_t* xq = (int8_t*)d_ws;
        int8_t* wq = xq + xq_bytes;
        float*  xs = (float*)(wq + wq_bytes);
        quant_x_kernel<<<M_DIM, 256, 0, stream>>>(x, xq, xs);
        unpack_w_kernel<<<(int)((size_t)N_DIM * K_DIM / 16 / 256), 256, 0, stream>>>(qw, wq);
        gemm_i8_kernel<<<dim3(N_DIM / BN, M_DIM / BM), THREADS, 0, stream>>>(xq, wq, xs, sc, bias, y);
    } else {
        fallback_kernel<<<dim3((N_DIM + 255) / 256, M_DIM), 256, 0, stream>>>(x, qw, sc, bias, y);
    }
}

// Round 5
// 875.656 us; speedup vs baseline: 1.1909x; 1.0107x over previous
//
#include <hip/hip_runtime.h>
#include <stdint.h>

#define M_DIM 8192
#define N_DIM 11008
#define K_DIM 4096
#define KB_PACK 2048          // packed int32 (one byte each) per W row

// ---- triple-buffered single-barrier pipeline geometry ----
#define BM 256
#define BN 256
#define BK 64                 // 64 i8 per row per k-step = one 16x16x64 MFMA K
#define NKT (K_DIM / BK)      // 64
#define THREADS 512

typedef __attribute__((ext_vector_type(4))) int   i32x4;
typedef __attribute__((ext_vector_type(4))) float f32x4;

// -------- async global->LDS (16B per lane; LDS dest = wave-uniform base + lane*16) --------
__device__ __forceinline__ void gload_lds16(const int8_t* g, int8_t* l) {
    __builtin_amdgcn_global_load_lds(
        (const __attribute__((address_space(1))) void*)g,
        (__attribute__((address_space(3))) void*)l,
        16, 0, 0);
}

// -------- pre-pass 1: per-row absmax int8 quantization of x --------
__global__ __launch_bounds__(256) void quant_x_kernel(const float* __restrict__ x,
                                                      int8_t* __restrict__ xq,
                                                      float* __restrict__ xs) {
    const int m   = blockIdx.x;
    const int tid = threadIdx.x;
    const float4* row = (const float4*)(x + (size_t)m * K_DIM);

    float4 v[4];
    float amax = 0.f;
#pragma unroll
    for (int i = 0; i < 4; ++i) {
        v[i] = row[i * 256 + tid];                       // coalesced
        amax = fmaxf(amax, fmaxf(fmaxf(fabsf(v[i].x), fabsf(v[i].y)),
                                 fmaxf(fabsf(v[i].z), fabsf(v[i].w))));
    }
#pragma unroll
    for (int off = 32; off > 0; off >>= 1)
        amax = fmaxf(amax, __shfl_xor(amax, off));
    __shared__ float red[4];
    if ((tid & 63) == 0) red[tid >> 6] = amax;
    __syncthreads();
    amax = fmaxf(fmaxf(red[0], red[1]), fmaxf(red[2], red[3]));

    const float safe = fmaxf(amax, 1e-20f);
    const float inv  = 127.f / safe;
    if (tid == 0) xs[m] = safe * (1.f / 127.f);

    int* out = (int*)(xq + (size_t)m * K_DIM);
#pragma unroll
    for (int i = 0; i < 4; ++i) {
        int c0 = __float2int_rn(v[i].x * inv);
        int c1 = __float2int_rn(v[i].y * inv);
        int c2 = __float2int_rn(v[i].z * inv);
        int c3 = __float2int_rn(v[i].w * inv);
        out[i * 256 + tid] = (c0 & 255) | ((c1 & 255) << 8) | ((c2 & 255) << 16) | (c3 << 24);
    }
}

// -------- pre-pass 2: unpack int4 (low nibble first) -> int8, scale folded into epilogue --------
__device__ __forceinline__ int unpack2(int v0, int v1) {
    int l0 = (((v0 & 15) ^ 8) - 8) & 255;
    int h0 = ((((v0 >> 4) & 15) ^ 8) - 8) & 255;
    int l1 = (((v1 & 15) ^ 8) - 8) & 255;
    int h1 = ((((v1 >> 4) & 15) ^ 8) - 8) & 255;
    return l0 | (h0 << 8) | (l1 << 16) | (h1 << 24);
}

__global__ __launch_bounds__(256) void unpack_w_kernel(const int* __restrict__ qw,
                                                       int8_t* __restrict__ wq) {
    size_t i = (size_t)blockIdx.x * 256 + threadIdx.x;
    const i32x4* q4 = (const i32x4*)qw;
    i32x4 a = q4[2 * i];
    i32x4 b = q4[2 * i + 1];
    i32x4 o;
    o.x = unpack2(a.x, a.y);
    o.y = unpack2(a.z, a.w);
    o.z = unpack2(b.x, b.y);
    o.w = unpack2(b.z, b.w);
    ((i32x4*)wq)[i] = o;
}

// ============ main GEMM: 256x256, BK=64, triple-buffered, ONE barrier per K-tile ============
// LDS (96 KiB): A bufs 3x16K @ {0,16384,32768}; B bufs 3x16K @ {49152,65536,81920}.
// Invariants:
//  (1) Tile kt reads ONLY buf[kt%3]; stages write ONLY buf[(kt+2)%3] -> disjoint, WAR-safe for
//      any wave drift (tile kt-1's reads are consumed via lgkm before its closing barrier, and
//      the overwrite of buf[(kt-1)%3] is issued after that barrier).
//  (2) ALL fragment reads of tile kt happen AFTER the barrier at end of tile kt-1, which every
//      wave reaches only after ITS vmcnt(4) proving tile kt landed — cross-wave LDS visibility
//      is barrier-established, never assumed from a single wave's vmcnt (round-3 bug, fixed).
//  (3) vmcnt(4) never drains the queue: 4 loads/tile, 4 always in flight across the barrier.
// vmcnt ledger: prologue 8 issued, wait->4 (tile0 landed). Each iter: +4 (8 in flight),
// wait->4 (tile kt+1 landed, tile kt+2 rides the barrier). Never 0, never unreachable.
__global__ __launch_bounds__(THREADS, 2) void gemm_i8_kernel(
    const int8_t* __restrict__ A,   // [M][K] i8
    const int8_t* __restrict__ B,   // [N][K] i8
    const float* __restrict__ xs,   // [M]
    const float* __restrict__ wsc,  // [N]
    const float* __restrict__ bias, // [N]
    float* __restrict__ C) {        // [M][N] fp32
    __shared__ int8_t lds[98304];

    const int tid  = threadIdx.x;
    const int lane = tid & 63;
    const int wid  = tid >> 6;
    const int wr   = wid >> 2;          // 0..1 : 128 output rows each
    const int wc   = wid & 3;           // 0..3 : 64 output cols each
    const int l15  = lane & 15;
    const int q    = lane >> 4;         // 16B k-chunk within BK

    // XCD-aware swizzle: 1376 blocks = 8 XCDs * 172 (exact, bijective); M varies fastest
    const int lin = blockIdx.y * gridDim.x + blockIdx.x;
    const int swz = (lin & 7) * 172 + (lin >> 3);
    const int m0  = (swz & 31) * BM;    // 32 M-tiles
    const int n0  = (swz >> 5) * BN;    // 43 N-tiles

    // ---------- staging map: linear LDS dest (t*16), inverse-swizzled global source ----------
    const int sr   = tid >> 2;                                   // row 0..127 within half
    const int scol = (((tid & 3) ^ ((tid >> 3) & 3)) << 4);      // global col pre-swizzled
    const int8_t* gA = A + (size_t)(m0 + sr) * K_DIM + scol;
    const int8_t* gB = B + (size_t)(n0 + sr) * K_DIM + scol;
    const int sdst = tid * 16;

#define STAGE_A(GK, DB) do { \
        const int8_t* g_ = gA + (size_t)(GK) * BK; \
        int8_t* d_ = lds + (DB) + sdst; \
        gload_lds16(g_, d_); \
        gload_lds16(g_ + (size_t)128 * K_DIM, d_ + 8192); \
    } while (0)
#define STAGE_B(GK, DB) do { \
        const int8_t* g_ = gB + (size_t)(GK) * BK; \
        int8_t* d_ = lds + (DB) + sdst; \
        gload_lds16(g_, d_); \
        gload_lds16(g_ + (size_t)128 * K_DIM, d_ + 8192); \
    } while (0)

    // ---------- fragment LDS offsets (swizzled read side, same involution as staging) ----------
    const int fswz = ((q ^ ((l15 >> 1) & 3)) << 4);
    const int aoff = (wr * 128 + l15) * 64 + fswz;   // + base + mi*1024
    const int boff = (wc * 64 + l15) * 64 + fswz;    // + base + ni*1024

#define LD(BASE, OFF) (*(const i32x4*)(lds + (BASE) + (OFF)))
#define MFMA(D, AOP, BOP) D = __builtin_amdgcn_mfma_i32_16x16x64_i8(AOP, BOP, D, 0, 0, 0)

    // rotating bases: rd = buf[kt%3], nx = buf[(kt+1)%3], st = buf[(kt+2)%3]
    int aRd = 0,     aNx = 16384, aSt = 32768;
    int bRd = 49152, bNx = 65536, bSt = 81920;

    i32x4 acc[8][4] = {};

    // ---------- prologue: ship tiles 0,1; own-vmcnt then BARRIER before any read ----------
    STAGE_A(0, aRd); STAGE_B(0, bRd);
    STAGE_A(1, aNx); STAGE_B(1, bNx);
    asm volatile("s_waitcnt vmcnt(4)" ::: "memory");   // tile0 landed (tile1's 4 in flight)
    __builtin_amdgcn_s_barrier();                      // => tile0 visible to ALL waves

    for (int kt = 0; kt < NKT; ++kt) {
        const int gk = (kt + 2 < NKT) ? kt + 2 : 0;    // tail: real address, never read
        // issue next-next tile stages first (independent, vmcnt-tracked)
        STAGE_A(gk, aSt);
        STAGE_B(gk, bSt);

        // fragment reads of tile kt — legal per invariant (2)
        i32x4 af[4], ag[4], bf[4];
#pragma unroll
        for (int i = 0; i < 4; ++i) af[i] = LD(aRd, aoff + i * 1024);
#pragma unroll
        for (int i = 0; i < 4; ++i) bf[i] = LD(bRd, boff + i * 1024);
#pragma unroll
        for (int i = 0; i < 4; ++i) ag[i] = LD(aRd, aoff + (4 + i) * 1024);

        __builtin_amdgcn_s_setprio(1);
#pragma unroll
        for (int mi = 0; mi < 4; ++mi)
#pragma unroll
            for (int ni = 0; ni < 4; ++ni) MFMA(acc[mi][ni], af[mi], bf[ni]);
#pragma unroll
        for (int mi = 0; mi < 4; ++mi)
#pragma unroll
            for (int ni = 0; ni < 4; ++ni) MFMA(acc[4 + mi][ni], ag[mi], bf[ni]);
        __builtin_amdgcn_s_setprio(0);

        asm volatile("s_waitcnt vmcnt(4)" ::: "memory");  // tile kt+1 landed (this wave)
        __builtin_amdgcn_s_barrier();                     // tile kt+1 visible to ALL waves

        // rotate bases forward one tile: (rd,nx,st) <- (nx,st,rd)
        int t;
        t = aRd; aRd = aNx; aNx = aSt; aSt = t;
        t = bRd; bRd = bNx; bNx = bSt; bSt = t;
    }

    // ---------- epilogue: C/D layout col = lane&15, row = (lane>>4)*4 + reg ----------
    const int row0 = q * 4;
    float sn[4], bv[4];
#pragma unroll
    for (int ni = 0; ni < 4; ++ni) {
        const int n = n0 + wc * 64 + ni * 16 + l15;
        sn[ni] = wsc[n];
        bv[ni] = bias[n];
    }
#pragma unroll
    for (int mi = 0; mi < 8; ++mi) {
        const int mbase = m0 + wr * 128 + mi * 16 + row0;
        float sm[4];
#pragma unroll
        for (int ri = 0; ri < 4; ++ri) sm[ri] = xs[mbase + ri];
#pragma unroll
        for (int ni = 0; ni < 4; ++ni) {
            const int n = n0 + wc * 64 + ni * 16 + l15;
            float* cp = C + (size_t)mbase * N_DIM + n;
#pragma unroll
            for (int ri = 0; ri < 4; ++ri)
                cp[(size_t)ri * N_DIM] = (float)acc[mi][ni][ri] * (sm[ri] * sn[ni]) + bv[ni];
        }
    }
#undef STAGE_A
#undef STAGE_B
#undef LD
#undef MFMA
}

// -------- fallback (only if workspace too small): naive fused dequant dot --------
__global__ void fallback_kernel(const float* __restrict__ x, const int* __restrict__ qw,
                                const float* __restrict__ sc, const float* __restrict__ bias,
                                float* __restrict__ y) {
    int m = blockIdx.y;
    int n = blockIdx.x * 256 + threadIdx.x;
    __shared__ float xsh[K_DIM];
    for (int k = threadIdx.x; k < K_DIM; k += 256) xsh[k] = x[(size_t)m * K_DIM + k];
    __syncthreads();
    if (n < N_DIM) {
        float acc = 0.f;
        const int* qr = qw + (size_t)n * KB_PACK;
        for (int kb = 0; kb < KB_PACK; ++kb) {
            int v = qr[kb] & 255;
            int lo = v & 15; lo -= (lo & 8) << 1;
            int hi = (v >> 4) & 15; hi -= (hi & 8) << 1;
            acc += xsh[2 * kb] * (float)lo + xsh[2 * kb + 1] * (float)hi;
        }
        y[(size_t)m * N_DIM + n] = acc * sc[n] + bias[n];
    }
}

extern "C" void kernel_launch(void* const* d_in, const int* in_sizes, int n_in,
                              void* d_out, int out_size, void* d_ws, size_t ws_size,
                              hipStream_t stream) {
    const float* x    = (const float*)d_in[0];
    const int*   qw   = (const int*)d_in[1];
    const float* sc   = (const float*)d_in[2];
    const float* bias = (const float*)d_in[3];
    float*       y    = (float*)d_out;

    const size_t xq_bytes = (size_t)M_DIM * K_DIM;            // 33.5 MB i8
    const size_t wq_bytes = (size_t)N_DIM * K_DIM;            // 45 MB i8
    const size_t xs_bytes = (size_t)M_DIM * sizeof(float);
    const size_t need = xq_bytes + wq_bytes + xs_bytes;

    if (ws_size >= need) {
        int8_t* xq = (int8_t*)d_ws;
        int8_t* wq = xq + xq_bytes;
        float*  xs = (float*)(wq + wq_bytes);
        quant_x_kernel<<<M_DIM, 256, 0, stream>>>(x, xq, xs);
        unpack_w_kernel<<<(int)((size_t)N_DIM * K_DIM / 16 / 256), 256, 0, stream>>>(qw, wq);
        gemm_i8_kernel<<<dim3(N_DIM / BN, M_DIM / BM), THREADS, 0, stream>>>(xq, wq, xs, sc, bias, y);
    } else {
        fallback_kernel<<<dim3((N_DIM + 255) / 256, M_DIM), 256, 0, stream>>>(x, qw, sc, bias, y);
    }
}